// Round 4
// baseline (463.769 us; speedup 1.0000x reference)
//
#include <hip/hip_runtime.h>
#include <math.h>

// x[8192,32] -> RBF(512,d32) -> Lin(64) -> RBF(512,d64) -> Lin(32), single fused kernel.
// 512 threads (8 waves), 16 rows/block, grid 512 (2 blocks/CU).
// Principles (round-3 postmortem): broadcast ds_read_b128 costs ~9.5cy (full VGPR
// writeback) regardless of address pattern -> minimize LDS instruction COUNT:
//  - RBF: multi-center register tiles, x/h broadcast amortized over 8/4 centers
//  - GEMM: 4 output cols/thread + in-wave K-split folded with DPP quad_perm (VALU-only)
//  - norms recomputed in-register; no prepack kernel; no d_ws

#define NROWS 8192
#define R 16
#define BLOCK 512
#define GRID (NROWS / R)

__device__ __forceinline__ float dpp_xor1_add(float v) {
    // += value from lane^1 (quad_perm [1,0,3,2] = 0xB1)
    int p = __builtin_amdgcn_update_dpp(0, __float_as_int(v), 0xB1, 0xF, 0xF, true);
    return v + __int_as_float(p);
}
__device__ __forceinline__ float dpp_xor2_add(float v) {
    // += value from lane^2 (quad_perm [2,3,0,1] = 0x4E)
    int p = __builtin_amdgcn_update_dpp(0, __float_as_int(v), 0x4E, 0xF, 0xF, true);
    return v + __int_as_float(p);
}

__global__ __launch_bounds__(BLOCK, 4)
void rbfnet(const float* __restrict__ x,
            const float* __restrict__ centers0, const float* __restrict__ ls0,
            const float* __restrict__ W0, const float* __restrict__ b0,
            const float* __restrict__ centers1, const float* __restrict__ ls1,
            const float* __restrict__ W1, const float* __restrict__ b1,
            float* __restrict__ out)
{
    // phi stride 516: 16B-aligned rows (516*4=2064=129*16), bank stride 4 -> <=2-way on writes
    __shared__ float phi[R][516];          // 33.0 KB
    __shared__ float h_lds[R][68];         // 4.35 KB
    __shared__ float hpart[8][R][66];      // 33.8 KB (bank-staggered partials)
    __shared__ float hn_lds[R];

    const int t = threadIdx.x;
    const int l = t & 63;
    const int w = t >> 6;                  // wave id 0..7
    const int row0 = blockIdx.x * R;

    // ================= RBF0: wave w owns rows {2w, 2w+1}; lane l owns centers {l+64i} =====
    {
        const int r0 = 2 * w;
        float dot0[8], dot1[8], cn[8];
        #pragma unroll
        for (int i = 0; i < 8; ++i) { dot0[i] = 0.f; dot1[i] = 0.f; cn[i] = 0.f; }
        float rn0 = 0.f, rn1 = 0.f;

        #pragma unroll
        for (int ch = 0; ch < 8; ++ch) {
            const float4 xv0 = *(const float4*)&x[(row0 + r0) * 32 + ch * 4];     // uniform -> L1/scalar
            const float4 xv1 = *(const float4*)&x[(row0 + r0 + 1) * 32 + ch * 4];
            rn0 += xv0.x*xv0.x + xv0.y*xv0.y + xv0.z*xv0.z + xv0.w*xv0.w;
            rn1 += xv1.x*xv1.x + xv1.y*xv1.y + xv1.z*xv1.z + xv1.w*xv1.w;
            #pragma unroll
            for (int i = 0; i < 8; ++i) {
                const float4 cv = *(const float4*)&centers0[(l + 64*i) * 32 + ch * 4];
                cn[i]   += cv.x*cv.x + cv.y*cv.y + cv.z*cv.z + cv.w*cv.w;
                dot0[i] += xv0.x*cv.x + xv0.y*cv.y + xv0.z*cv.z + xv0.w*cv.w;
                dot1[i] += xv1.x*cv.x + xv1.y*cv.y + xv1.z*cv.z + xv1.w*cv.w;
            }
        }
        #pragma unroll
        for (int i = 0; i < 8; ++i) {
            const int c = l + 64*i;
            const float iv = __expf(-2.0f * ls0[c]);
            phi[r0    ][c] = __expf(iv * (2.f*dot0[i] - rn0 - cn[i]));
            phi[r0 + 1][c] = __expf(iv * (2.f*dot1[i] - rn1 - cn[i]));
        }
    }
    __syncthreads();

    // ================= GEMM0: h[16][64]; lane=(slow1,jq4,rh1); 16 K-splits ===========
    // s = w*2+slow covers 32 c's; 4 j's per thread; DPP xor1 folds slow pairs.
    {
        const int slow = l & 1;
        const int jq   = (l >> 1) & 15;
        const int rh   = l >> 5;
        const int s    = w * 2 + slow;
        float acc[4][8];
        #pragma unroll
        for (int jj = 0; jj < 4; ++jj)
            #pragma unroll
            for (int rr = 0; rr < 8; ++rr) acc[jj][rr] = 0.f;

        #pragma unroll
        for (int i = 0; i < 8; ++i) {
            const int c4 = s * 8 + i;
            const float4 wv0 = *(const float4*)&W0[(jq*4 + 0)*512 + c4*4];
            const float4 wv1 = *(const float4*)&W0[(jq*4 + 1)*512 + c4*4];
            const float4 wv2 = *(const float4*)&W0[(jq*4 + 2)*512 + c4*4];
            const float4 wv3 = *(const float4*)&W0[(jq*4 + 3)*512 + c4*4];
            #pragma unroll
            for (int rr = 0; rr < 8; ++rr) {
                const float4 p = *(const float4*)&phi[rh*8 + rr][c4*4];
                acc[0][rr] += wv0.x*p.x + wv0.y*p.y + wv0.z*p.z + wv0.w*p.w;
                acc[1][rr] += wv1.x*p.x + wv1.y*p.y + wv1.z*p.z + wv1.w*p.w;
                acc[2][rr] += wv2.x*p.x + wv2.y*p.y + wv2.z*p.z + wv2.w*p.w;
                acc[3][rr] += wv3.x*p.x + wv3.y*p.y + wv3.z*p.z + wv3.w*p.w;
            }
        }
        #pragma unroll
        for (int jj = 0; jj < 4; ++jj)
            #pragma unroll
            for (int rr = 0; rr < 8; ++rr) acc[jj][rr] = dpp_xor1_add(acc[jj][rr]);
        if (slow == 0) {
            #pragma unroll
            for (int rr = 0; rr < 8; ++rr)
                #pragma unroll
                for (int jj = 0; jj < 4; jj += 2)
                    *(float2*)&hpart[w][rh*8 + rr][jq*4 + jj] =
                        make_float2(acc[jj][rr], acc[jj+1][rr]);
        }
    }
    __syncthreads();

    // ---- reduce 8 wave-partials -> h_lds (+bias) ----
    {
        const int j  = t & 63;
        const int r2 = t >> 6;             // 0..7
        const float bj = b0[j];
        #pragma unroll
        for (int rr = 0; rr < 2; ++rr) {
            const int r = r2 + rr*8;
            float s = 0.f;
            #pragma unroll
            for (int k = 0; k < 8; ++k) s += hpart[k][r][j];
            h_lds[r][j] = s + bj;
        }
    }
    __syncthreads();
    // ---- hn via shfl tree (32 lanes/row) ----
    {
        const int rl = t >> 5, d = t & 31;
        const float v0 = h_lds[rl][d], v1 = h_lds[rl][d + 32];
        float s = v0*v0 + v1*v1;
        s += __shfl_xor(s, 1);  s += __shfl_xor(s, 2);  s += __shfl_xor(s, 4);
        s += __shfl_xor(s, 8);  s += __shfl_xor(s, 16);
        if (d == 0) hn_lds[rl] = s;
    }
    __syncthreads();

    // ================= RBF1: wave-pair owns 4 rows; lane owns centers {cg+128i} =======
    {
        const int cg = (w & 1) * 64 + l;   // 0..127
        const int rb = (w >> 1) * 4;       // row base, wave-uniform
        float dot[4][4], cn[4];
        #pragma unroll
        for (int i = 0; i < 4; ++i) {
            cn[i] = 0.f;
            #pragma unroll
            for (int rr = 0; rr < 4; ++rr) dot[i][rr] = 0.f;
        }
        #pragma unroll
        for (int ch = 0; ch < 16; ++ch) {
            float4 hv[4];
            #pragma unroll
            for (int rr = 0; rr < 4; ++rr) hv[rr] = *(const float4*)&h_lds[rb + rr][ch*4];
            #pragma unroll
            for (int i = 0; i < 4; ++i) {
                const float4 cv = *(const float4*)&centers1[(cg + 128*i)*64 + ch*4];
                cn[i] += cv.x*cv.x + cv.y*cv.y + cv.z*cv.z + cv.w*cv.w;
                #pragma unroll
                for (int rr = 0; rr < 4; ++rr)
                    dot[i][rr] += hv[rr].x*cv.x + hv[rr].y*cv.y + hv[rr].z*cv.z + hv[rr].w*cv.w;
            }
        }
        float hnr[4];
        #pragma unroll
        for (int rr = 0; rr < 4; ++rr) hnr[rr] = hn_lds[rb + rr];
        #pragma unroll
        for (int i = 0; i < 4; ++i) {
            const int c = cg + 128*i;
            const float iv = __expf(-2.0f * ls1[c]);
            #pragma unroll
            for (int rr = 0; rr < 4; ++rr)
                phi[rb + rr][c] = __expf(iv * (2.f*dot[i][rr] - hnr[rr] - cn[i]));
        }
    }
    __syncthreads();

    // ================= GEMM1: out[16][32]; lane=(slow2,jq3,rh1); 32 K-splits ==========
    {
        const int slow = l & 3;
        const int jq   = (l >> 2) & 7;
        const int rh   = l >> 5;
        const int s    = w * 4 + slow;     // 0..31
        float acc[4][8];
        #pragma unroll
        for (int jj = 0; jj < 4; ++jj)
            #pragma unroll
            for (int rr = 0; rr < 8; ++rr) acc[jj][rr] = 0.f;

        #pragma unroll
        for (int i = 0; i < 4; ++i) {
            const int c4 = s * 4 + i;      // 0..127
            const float4 wv0 = *(const float4*)&W1[(jq*4 + 0)*512 + c4*4];
            const float4 wv1 = *(const float4*)&W1[(jq*4 + 1)*512 + c4*4];
            const float4 wv2 = *(const float4*)&W1[(jq*4 + 2)*512 + c4*4];
            const float4 wv3 = *(const float4*)&W1[(jq*4 + 3)*512 + c4*4];
            #pragma unroll
            for (int rr = 0; rr < 8; ++rr) {
                const float4 p = *(const float4*)&phi[rh*8 + rr][c4*4];
                acc[0][rr] += wv0.x*p.x + wv0.y*p.y + wv0.z*p.z + wv0.w*p.w;
                acc[1][rr] += wv1.x*p.x + wv1.y*p.y + wv1.z*p.z + wv1.w*p.w;
                acc[2][rr] += wv2.x*p.x + wv2.y*p.y + wv2.z*p.z + wv2.w*p.w;
                acc[3][rr] += wv3.x*p.x + wv3.y*p.y + wv3.z*p.z + wv3.w*p.w;
            }
        }
        #pragma unroll
        for (int jj = 0; jj < 4; ++jj)
            #pragma unroll
            for (int rr = 0; rr < 8; ++rr) {
                acc[jj][rr] = dpp_xor1_add(acc[jj][rr]);
                acc[jj][rr] = dpp_xor2_add(acc[jj][rr]);
            }
        if (slow == 0) {
            #pragma unroll
            for (int rr = 0; rr < 8; ++rr)
                #pragma unroll
                for (int jj = 0; jj < 4; jj += 2)
                    *(float2*)&hpart[w][rh*8 + rr][jq*4 + jj] =
                        make_float2(acc[jj][rr], acc[jj+1][rr]);
        }
    }
    __syncthreads();

    // ---- final reduce + bias + store ----
    {
        const int r = t >> 5, j = t & 31;
        float s = 0.f;
        #pragma unroll
        for (int k = 0; k < 8; ++k) s += hpart[k][r][j];
        out[(row0 + r) * 32 + j] = s + b1[j];
    }
}

extern "C" void kernel_launch(void* const* d_in, const int* in_sizes, int n_in,
                              void* d_out, int out_size, void* d_ws, size_t ws_size,
                              hipStream_t stream) {
    const float* xin = (const float*)d_in[0];
    const float* c0  = (const float*)d_in[1];
    const float* ls0 = (const float*)d_in[2];
    const float* W0  = (const float*)d_in[3];
    const float* b0  = (const float*)d_in[4];
    const float* c1  = (const float*)d_in[5];
    const float* ls1 = (const float*)d_in[6];
    const float* W1  = (const float*)d_in[7];
    const float* b1  = (const float*)d_in[8];
    float* outp = (float*)d_out;

    hipLaunchKernelGGL(rbfnet, dim3(GRID), dim3(BLOCK), 0, stream,
                       xin, c0, ls0, W0, b0, c1, ls1, W1, b1, outp);
}

// Round 5
// 92.374 us; speedup vs baseline: 5.0206x; 5.0206x over previous
//
#include <hip/hip_runtime.h>
#include <math.h>

// x[8192,32] -> RBF(512,d32) -> Lin(64) -> RBF(512,d64) -> Lin(32), single fused kernel.
// All four contractions via v_mfma_f32_16x16x32_bf16 (M=16 = rows/block).
// Layouts (guide §3, m89-verified): A: row=l&15, k=(l>>4)*8+i ; B: col=l&15, same k;
// D: col=l&15, row=(l>>4)*4+reg.  phi stored bf16 in LDS [16][520] (2-way-max banks);
// B-fragments (centers/W) loaded from global per wave; center norms folded into the
// B-load and reduced with shfl_xor(16/32) — no LDS. Split across 8 waves:
//   RBF0/RBF1: wave w owns centers [64w,64w+64) (4 n-tiles)
//   GEMM0: (nt=w&3, K-half=w>>2) ; GEMM1: (nt=w&1, K-quarter=w>>1); partials in LDS.
// Round-4 lesson: #pragma unroll 1 on every loop containing global loads.

#define NROWS 8192
#define R 16
#define BLOCK 512
#define GRID (NROWS / R)

typedef __attribute__((ext_vector_type(8))) short short8;
typedef __attribute__((ext_vector_type(4))) float f32x4;

__device__ __forceinline__ short bf16t(float f) {
    return (short)(__float_as_uint(f) >> 16);   // truncate; precision ample here
}

__global__ __launch_bounds__(BLOCK, 4)
void rbfnet(const float* __restrict__ x,
            const float* __restrict__ c0, const float* __restrict__ ls0,
            const float* __restrict__ W0, const float* __restrict__ b0,
            const float* __restrict__ c1, const float* __restrict__ ls1,
            const float* __restrict__ W1, const float* __restrict__ b1,
            float* __restrict__ out)
{
    __shared__ unsigned short phi_u[16 * 520];  // bf16 phi, row stride 520 (2-way banks)
    __shared__ float h_lds[16][68];
    __shared__ float htmp[2][16][68];           // GEMM0 K-half partials
    __shared__ float otmp[4][16][36];           // GEMM1 K-quarter partials
    __shared__ float rn_lds[16], hn_lds[16];

    const int t  = threadIdx.x;
    const int l  = t & 63;
    const int w  = t >> 6;       // wave 0..7
    const int mr = l & 15;       // MFMA row (A/D-col) index
    const int kg = l >> 4;       // k-group 0..3
    const int row0 = blockIdx.x * R;

    // ---------- Phase A: x A-fragment + row norms (in-register + 2 shuffles) ----------
    short8 ax;
    {
        const float4 x0 = *(const float4*)&x[(row0 + mr) * 32 + kg * 8];
        const float4 x1 = *(const float4*)&x[(row0 + mr) * 32 + kg * 8 + 4];
        const float xo[8] = {x0.x, x0.y, x0.z, x0.w, x1.x, x1.y, x1.z, x1.w};
        float rp = 0.f;
        #pragma unroll
        for (int i = 0; i < 8; ++i) { ax[i] = bf16t(xo[i]); rp += xo[i] * xo[i]; }
        rp += __shfl_xor(rp, 16);
        rp += __shfl_xor(rp, 32);
        if (t < 16) rn_lds[t] = rp;             // lane t holds norm of row t
    }
    __syncthreads();

    // ---------- Phase B: RBF0 — dots via MFMA (K=32, 1 step), 4 n-tiles/wave ----------
    {
        float rnv[4];
        #pragma unroll
        for (int g = 0; g < 4; ++g) rnv[g] = rn_lds[kg * 4 + g];
        #pragma unroll 1
        for (int q = 0; q < 4; ++q) {
            const int c = 64 * w + 16 * q + mr;
            const float4 cv0 = *(const float4*)&c0[c * 32 + kg * 8];
            const float4 cv1 = *(const float4*)&c0[c * 32 + kg * 8 + 4];
            const float co[8] = {cv0.x, cv0.y, cv0.z, cv0.w, cv1.x, cv1.y, cv1.z, cv1.w};
            short8 bc;
            float cp = 0.f;
            #pragma unroll
            for (int i = 0; i < 8; ++i) { bc[i] = bf16t(co[i]); cp += co[i] * co[i]; }
            cp += __shfl_xor(cp, 16);
            cp += __shfl_xor(cp, 32);           // full ||c||^2 (4 k-groups)
            f32x4 d = {0.f, 0.f, 0.f, 0.f};
            d = __builtin_amdgcn_mfma_f32_16x16x32_bf16(ax, bc, d, 0, 0, 0);
            const float iv = __expf(-2.0f * ls0[c]);
            #pragma unroll
            for (int g = 0; g < 4; ++g) {
                const float p = __expf(-(rnv[g] + cp - 2.f * d[g]) * iv);
                phi_u[(kg * 4 + g) * 520 + c] = (unsigned short)bf16t(p);
            }
        }
    }
    __syncthreads();

    // ---------- Phase C: GEMM0 h = phi @ W0^T  (nt=w&3, K-half=w>>2) ----------
    {
        const int half = w >> 2;
        const int j = 16 * (w & 3) + mr;
        f32x4 hD = {0.f, 0.f, 0.f, 0.f};
        #pragma unroll 1
        for (int ks = 8 * half; ks < 8 * half + 8; ++ks) {
            const short8 ap = *(const short8*)&phi_u[mr * 520 + 32 * ks + kg * 8];
            const float4 w0v = *(const float4*)&W0[j * 512 + 32 * ks + kg * 8];
            const float4 w1v = *(const float4*)&W0[j * 512 + 32 * ks + kg * 8 + 4];
            const float wo[8] = {w0v.x, w0v.y, w0v.z, w0v.w, w1v.x, w1v.y, w1v.z, w1v.w};
            short8 bw;
            #pragma unroll
            for (int i = 0; i < 8; ++i) bw[i] = bf16t(wo[i]);
            hD = __builtin_amdgcn_mfma_f32_16x16x32_bf16(ap, bw, hD, 0, 0, 0);
        }
        #pragma unroll
        for (int g = 0; g < 4; ++g) htmp[half][kg * 4 + g][j] = hD[g];
    }
    __syncthreads();

    // ---------- Phase D: assemble h (+bias), then hn via shfl tree ----------
    {
        const int j = t & 63;
        const int r0 = t >> 6;
        const float bj = b0[j];
        #pragma unroll
        for (int rr = 0; rr < 2; ++rr) {
            const int r = r0 + 8 * rr;
            h_lds[r][j] = htmp[0][r][j] + htmp[1][r][j] + bj;
        }
    }
    __syncthreads();
    {
        const int r = t >> 5, d = t & 31;
        const float v0 = h_lds[r][d], v1 = h_lds[r][d + 32];
        float s = v0 * v0 + v1 * v1;
        s += __shfl_xor(s, 1);  s += __shfl_xor(s, 2);  s += __shfl_xor(s, 4);
        s += __shfl_xor(s, 8);  s += __shfl_xor(s, 16);
        if (d == 0) hn_lds[r] = s;
    }
    __syncthreads();

    // ---------- Phase E: RBF1 — dots via MFMA (K=64, 2 steps), 4 n-tiles/wave ----------
    {
        short8 ah0, ah1;
        {
            const float4 h0 = *(const float4*)&h_lds[mr][kg * 8];
            const float4 h1 = *(const float4*)&h_lds[mr][kg * 8 + 4];
            const float4 h2 = *(const float4*)&h_lds[mr][32 + kg * 8];
            const float4 h3 = *(const float4*)&h_lds[mr][32 + kg * 8 + 4];
            ah0[0]=bf16t(h0.x); ah0[1]=bf16t(h0.y); ah0[2]=bf16t(h0.z); ah0[3]=bf16t(h0.w);
            ah0[4]=bf16t(h1.x); ah0[5]=bf16t(h1.y); ah0[6]=bf16t(h1.z); ah0[7]=bf16t(h1.w);
            ah1[0]=bf16t(h2.x); ah1[1]=bf16t(h2.y); ah1[2]=bf16t(h2.z); ah1[3]=bf16t(h2.w);
            ah1[4]=bf16t(h3.x); ah1[5]=bf16t(h3.y); ah1[6]=bf16t(h3.z); ah1[7]=bf16t(h3.w);
        }
        float hnv[4];
        #pragma unroll
        for (int g = 0; g < 4; ++g) hnv[g] = hn_lds[kg * 4 + g];
        #pragma unroll 1
        for (int q = 0; q < 4; ++q) {
            const int c = 64 * w + 16 * q + mr;
            const float4 a0 = *(const float4*)&c1[c * 64 + kg * 8];
            const float4 a1 = *(const float4*)&c1[c * 64 + kg * 8 + 4];
            const float4 a2 = *(const float4*)&c1[c * 64 + 32 + kg * 8];
            const float4 a3 = *(const float4*)&c1[c * 64 + 32 + kg * 8 + 4];
            const float co[16] = {a0.x,a0.y,a0.z,a0.w, a1.x,a1.y,a1.z,a1.w,
                                  a2.x,a2.y,a2.z,a2.w, a3.x,a3.y,a3.z,a3.w};
            short8 bc0, bc1;
            float cp = 0.f;
            #pragma unroll
            for (int i = 0; i < 8; ++i)  { bc0[i] = bf16t(co[i]);     cp += co[i] * co[i]; }
            #pragma unroll
            for (int i = 0; i < 8; ++i)  { bc1[i] = bf16t(co[8 + i]); cp += co[8+i] * co[8+i]; }
            cp += __shfl_xor(cp, 16);
            cp += __shfl_xor(cp, 32);
            f32x4 d = {0.f, 0.f, 0.f, 0.f};
            d = __builtin_amdgcn_mfma_f32_16x16x32_bf16(ah0, bc0, d, 0, 0, 0);
            d = __builtin_amdgcn_mfma_f32_16x16x32_bf16(ah1, bc1, d, 0, 0, 0);
            const float iv = __expf(-2.0f * ls1[c]);
            #pragma unroll
            for (int g = 0; g < 4; ++g) {
                const float p = __expf(-(hnv[g] + cp - 2.f * d[g]) * iv);
                phi_u[(kg * 4 + g) * 520 + c] = (unsigned short)bf16t(p);
            }
        }
    }
    __syncthreads();

    // ---------- Phase F: GEMM1 out = phi1 @ W1^T  (nt=w&1, K-quarter=w>>1) ----------
    {
        const int qtr = w >> 1;
        const int j = 16 * (w & 1) + mr;
        f32x4 oD = {0.f, 0.f, 0.f, 0.f};
        #pragma unroll 1
        for (int ks = 4 * qtr; ks < 4 * qtr + 4; ++ks) {
            const short8 ap = *(const short8*)&phi_u[mr * 520 + 32 * ks + kg * 8];
            const float4 w0v = *(const float4*)&W1[j * 512 + 32 * ks + kg * 8];
            const float4 w1v = *(const float4*)&W1[j * 512 + 32 * ks + kg * 8 + 4];
            const float wo[8] = {w0v.x, w0v.y, w0v.z, w0v.w, w1v.x, w1v.y, w1v.z, w1v.w};
            short8 bw;
            #pragma unroll
            for (int i = 0; i < 8; ++i) bw[i] = bf16t(wo[i]);
            oD = __builtin_amdgcn_mfma_f32_16x16x32_bf16(ap, bw, oD, 0, 0, 0);
        }
        #pragma unroll
        for (int g = 0; g < 4; ++g) otmp[qtr][kg * 4 + g][j] = oD[g];
    }
    __syncthreads();

    // ---------- Phase G: final reduce + bias + coalesced store ----------
    {
        const int r = t >> 5, j = t & 31;
        const float s = otmp[0][r][j] + otmp[1][r][j] + otmp[2][r][j] + otmp[3][r][j] + b1[j];
        out[(row0 + r) * 32 + j] = s;
    }
}

extern "C" void kernel_launch(void* const* d_in, const int* in_sizes, int n_in,
                              void* d_out, int out_size, void* d_ws, size_t ws_size,
                              hipStream_t stream) {
    const float* xin = (const float*)d_in[0];
    const float* c0  = (const float*)d_in[1];
    const float* ls0 = (const float*)d_in[2];
    const float* W0  = (const float*)d_in[3];
    const float* b0  = (const float*)d_in[4];
    const float* c1  = (const float*)d_in[5];
    const float* ls1 = (const float*)d_in[6];
    const float* W1  = (const float*)d_in[7];
    const float* b1  = (const float*)d_in[8];
    float* outp = (float*)d_out;

    hipLaunchKernelGGL(rbfnet, dim3(GRID), dim3(BLOCK), 0, stream,
                       xin, c0, ls0, W0, b0, c1, ls1, W1, b1, outp);
}

// Round 7
// 79.081 us; speedup vs baseline: 5.8645x; 1.1681x over previous
//
#include <hip/hip_runtime.h>
#include <math.h>

// x[8192,32] -> RBF(512,d32) -> Lin(64) -> RBF(512,d64) -> Lin(32), MFMA everywhere.
// Round-6 (resubmit; round-6 bench was an acquisition timeout, kernel never ran):
// prepack params into bf16 MFMA B-fragment order (d_ws) so the hot kernel's
// B-operands are single coalesced b128 loads; cn/iv precomputed; 5 barriers; unroll-2
// prefetch (round-4 lesson: never full-unroll grouped global loads).
// Fragment maps (m89-verified, validated round 5): A row=l&15,k=(l>>4)*8+e;
// B col=l&15,k=(l>>4)*8+e; D col=l&15,row=(l>>4)*4+g.

#define NROWS 8192
#define BLOCK 512
#define GRID (NROWS / 16)

typedef __attribute__((ext_vector_type(8))) short short8;
typedef __attribute__((ext_vector_type(4))) float f32x4;

__device__ __forceinline__ short bf16t(float f) {
    return (short)(__float_as_uint(f) >> 16);
}

// ---------------- prepack: params -> bf16 B-frags + cn/iv ----------------
// ws layout (bytes):
//   wpc0 [nt32][l64][e8] u16           @ 0       (32 KB)
//   wpc1 [nt32][kk2][l64][e8] u16      @ 32768   (64 KB)
//   wpw0 [ks16][nt4][l64][e8] u16      @ 98304   (64 KB)
//   wpw1 [ks16][nt2][l64][e8] u16      @ 163840  (32 KB)
//   cniv0 float2[512]                  @ 196608  (4 KB)
//   cniv1 float2[512]                  @ 200704  (4 KB)
__global__ void prepack(const float* __restrict__ c0, const float* __restrict__ ls0,
                        const float* __restrict__ W0,
                        const float* __restrict__ c1, const float* __restrict__ ls1,
                        const float* __restrict__ W1,
                        unsigned short* __restrict__ wpc0, unsigned short* __restrict__ wpc1,
                        unsigned short* __restrict__ wpw0, unsigned short* __restrict__ wpw1,
                        float2* __restrict__ cniv0, float2* __restrict__ cniv1)
{
    const int i = blockIdx.x * 256 + threadIdx.x;
    if (i < 16384) {                    // wpc0: i = (nt*64+l)*8+e
        const int e = i & 7, l = (i >> 3) & 63, nt = i >> 9;
        const int c = nt * 16 + (l & 15), k = (l >> 4) * 8 + e;
        wpc0[i] = (unsigned short)bf16t(c0[c * 32 + k]);
    } else if (i < 49152) {             // wpc1: j = ((nt*2+kk)*64+l)*8+e
        const int j = i - 16384;
        const int e = j & 7, l = (j >> 3) & 63, kk = (j >> 9) & 1, nt = j >> 10;
        const int c = nt * 16 + (l & 15), k = kk * 32 + (l >> 4) * 8 + e;
        wpc1[j] = (unsigned short)bf16t(c1[c * 64 + k]);
    } else if (i < 81920) {             // wpw0: j = ((ks*4+nt)*64+l)*8+e
        const int j = i - 49152;
        const int e = j & 7, l = (j >> 3) & 63, nt = (j >> 9) & 3, ks = j >> 11;
        const int col = nt * 16 + (l & 15), k = ks * 32 + (l >> 4) * 8 + e;
        wpw0[j] = (unsigned short)bf16t(W0[col * 512 + k]);
    } else if (i < 98304) {             // wpw1: j = ((ks*2+nt)*64+l)*8+e
        const int j = i - 81920;
        const int e = j & 7, l = (j >> 3) & 63, nt = (j >> 9) & 1, ks = j >> 10;
        const int col = nt * 16 + (l & 15), k = ks * 32 + (l >> 4) * 8 + e;
        wpw1[j] = (unsigned short)bf16t(W1[col * 512 + k]);
    } else if (i < 98304 + 512) {       // cniv0
        const int c = i - 98304;
        float s = 0.f;
        for (int d = 0; d < 32; ++d) { const float v = c0[c * 32 + d]; s += v * v; }
        cniv0[c] = make_float2(s, __expf(-2.0f * ls0[c]));
    } else if (i < 98304 + 1024) {      // cniv1
        const int c = i - 98816;
        float s = 0.f;
        for (int d = 0; d < 64; ++d) { const float v = c1[c * 64 + d]; s += v * v; }
        cniv1[c] = make_float2(s, __expf(-2.0f * ls1[c]));
    }
}

// ---------------- main fused kernel ----------------
__global__ __launch_bounds__(BLOCK, 4)
void rbfnet(const float* __restrict__ x,
            const float* __restrict__ b0, const float* __restrict__ b1,
            const unsigned short* __restrict__ wpc0, const unsigned short* __restrict__ wpc1,
            const unsigned short* __restrict__ wpw0, const unsigned short* __restrict__ wpw1,
            const float2* __restrict__ cniv0, const float2* __restrict__ cniv1,
            float* __restrict__ out)
{
    __shared__ unsigned short phi_u[16 * 520];   // bf16 phi, stride 520 (min-cycle frag reads)
    __shared__ unsigned short hfrag[16 * 72];    // bf16 h, stride 72 (conflict-free b128)
    __shared__ float htmp[2][16][68];            // GEMM0 K-half partials
    __shared__ float otmp[4][16][36];            // GEMM1 K-quarter partials
    __shared__ float hn_lds[16];

    const int t  = threadIdx.x;
    const int l  = t & 63;
    const int w  = t >> 6;        // wave 0..7
    const int mr = l & 15;
    const int kg = l >> 4;
    const int row0 = blockIdx.x * 16;

    // ---- Phase A: x A-frag + row norms, register-only (no barrier) ----
    short8 ax;
    float rnv[4];
    {
        const float4 x0 = *(const float4*)&x[(row0 + mr) * 32 + kg * 8];
        const float4 x1 = *(const float4*)&x[(row0 + mr) * 32 + kg * 8 + 4];
        const float xo[8] = {x0.x, x0.y, x0.z, x0.w, x1.x, x1.y, x1.z, x1.w};
        float rp = 0.f;
        #pragma unroll
        for (int i = 0; i < 8; ++i) { ax[i] = bf16t(xo[i]); rp += xo[i] * xo[i]; }
        rp += __shfl_xor(rp, 16);
        rp += __shfl_xor(rp, 32);            // lane l now holds ||x_row(l&15)||^2
        #pragma unroll
        for (int g = 0; g < 4; ++g) rnv[g] = __shfl(rp, 4 * kg + g);
    }

    // ---- Phase B: RBF0, wave w owns n-tiles 4w..4w+3 ----
    {
        #pragma unroll 2
        for (int q = 0; q < 4; ++q) {
            const int nt = 4 * w + q;
            const int c  = nt * 16 + mr;
            const short8 bc = *(const short8*)&wpc0[(nt * 64 + l) * 8];
            const float2 cv = cniv0[c];
            f32x4 d = {0.f, 0.f, 0.f, 0.f};
            d = __builtin_amdgcn_mfma_f32_16x16x32_bf16(ax, bc, d, 0, 0, 0);
            #pragma unroll
            for (int g = 0; g < 4; ++g) {
                const float p = __expf(-(rnv[g] + cv.x - 2.f * d[g]) * cv.y);
                phi_u[(4 * kg + g) * 520 + c] = (unsigned short)bf16t(p);
            }
        }
    }
    __syncthreads();                                       // B1: phi0 complete

    // ---- Phase C: GEMM0 h = phi @ W0^T ; wave -> (nt=w&3, half=w>>2) ----
    {
        const int nt = w & 3, half = w >> 2;
        f32x4 hD = {0.f, 0.f, 0.f, 0.f};
        #pragma unroll 2
        for (int ks = 8 * half; ks < 8 * half + 8; ++ks) {
            const short8 ap = *(const short8*)&phi_u[mr * 520 + ks * 32 + kg * 8];
            const short8 bw = *(const short8*)&wpw0[((ks * 4 + nt) * 64 + l) * 8];
            hD = __builtin_amdgcn_mfma_f32_16x16x32_bf16(ap, bw, hD, 0, 0, 0);
        }
        #pragma unroll
        for (int g = 0; g < 4; ++g) htmp[half][4 * kg + g][nt * 16 + mr] = hD[g];
    }
    __syncthreads();                                       // B2: htmp complete

    // ---- Phase D: assemble h (+bias) -> bf16 frag LDS + hn tree, one pass ----
    {
        const int r = t >> 5, dd = t & 31;
        const float h0 = htmp[0][r][dd]      + htmp[1][r][dd]      + b0[dd];
        const float h1 = htmp[0][r][dd + 32] + htmp[1][r][dd + 32] + b0[dd + 32];
        hfrag[r * 72 + dd]      = (unsigned short)bf16t(h0);
        hfrag[r * 72 + 32 + dd] = (unsigned short)bf16t(h1);
        float s = h0 * h0 + h1 * h1;
        s += __shfl_xor(s, 1);  s += __shfl_xor(s, 2);  s += __shfl_xor(s, 4);
        s += __shfl_xor(s, 8);  s += __shfl_xor(s, 16);
        if (dd == 0) hn_lds[r] = s;
    }
    __syncthreads();                                       // B3: h + hn ready

    // ---- Phase E: RBF1 (K=64, 2 MFMA), wave w owns n-tiles 4w..4w+3 ----
    {
        const short8 ah0 = *(const short8*)&hfrag[mr * 72 + kg * 8];
        const short8 ah1 = *(const short8*)&hfrag[mr * 72 + 32 + kg * 8];
        float hnv[4];
        #pragma unroll
        for (int g = 0; g < 4; ++g) hnv[g] = hn_lds[4 * kg + g];
        #pragma unroll 2
        for (int q = 0; q < 4; ++q) {
            const int nt = 4 * w + q;
            const int c  = nt * 16 + mr;
            const short8 bc0 = *(const short8*)&wpc1[((nt * 2 + 0) * 64 + l) * 8];
            const short8 bc1 = *(const short8*)&wpc1[((nt * 2 + 1) * 64 + l) * 8];
            const float2 cv = cniv1[c];
            f32x4 d = {0.f, 0.f, 0.f, 0.f};
            d = __builtin_amdgcn_mfma_f32_16x16x32_bf16(ah0, bc0, d, 0, 0, 0);
            d = __builtin_amdgcn_mfma_f32_16x16x32_bf16(ah1, bc1, d, 0, 0, 0);
            #pragma unroll
            for (int g = 0; g < 4; ++g) {
                const float p = __expf(-(hnv[g] + cv.x - 2.f * d[g]) * cv.y);
                phi_u[(4 * kg + g) * 520 + c] = (unsigned short)bf16t(p);
            }
        }
    }
    __syncthreads();                                       // B4: phi1 complete

    // ---- Phase F: GEMM1 out = phi1 @ W1^T ; wave -> (nt=w&1, qtr=w>>1) ----
    {
        const int nt = w & 1, qtr = w >> 1;
        f32x4 oD = {0.f, 0.f, 0.f, 0.f};
        #pragma unroll 2
        for (int ks = 4 * qtr; ks < 4 * qtr + 4; ++ks) {
            const short8 ap = *(const short8*)&phi_u[mr * 520 + ks * 32 + kg * 8];
            const short8 bw = *(const short8*)&wpw1[((ks * 2 + nt) * 64 + l) * 8];
            oD = __builtin_amdgcn_mfma_f32_16x16x32_bf16(ap, bw, oD, 0, 0, 0);
        }
        #pragma unroll
        for (int g = 0; g < 4; ++g) otmp[qtr][4 * kg + g][nt * 16 + mr] = oD[g];
    }
    __syncthreads();                                       // B5: otmp complete

    // ---- Phase G: reduce 4 K-quarters + bias, coalesced store ----
    {
        const int r = t >> 5, j = t & 31;
        const float s = otmp[0][r][j] + otmp[1][r][j] + otmp[2][r][j] + otmp[3][r][j] + b1[j];
        out[(row0 + r) * 32 + j] = s;
    }
}

extern "C" void kernel_launch(void* const* d_in, const int* in_sizes, int n_in,
                              void* d_out, int out_size, void* d_ws, size_t ws_size,
                              hipStream_t stream) {
    const float* xin = (const float*)d_in[0];
    const float* c0  = (const float*)d_in[1];
    const float* ls0 = (const float*)d_in[2];
    const float* W0  = (const float*)d_in[3];
    const float* b0  = (const float*)d_in[4];
    const float* c1  = (const float*)d_in[5];
    const float* ls1 = (const float*)d_in[6];
    const float* W1  = (const float*)d_in[7];
    const float* b1  = (const float*)d_in[8];
    float* outp = (float*)d_out;

    char* ws = (char*)d_ws;
    unsigned short* wpc0 = (unsigned short*)(ws);
    unsigned short* wpc1 = (unsigned short*)(ws + 32768);
    unsigned short* wpw0 = (unsigned short*)(ws + 98304);
    unsigned short* wpw1 = (unsigned short*)(ws + 163840);
    float2* cniv0 = (float2*)(ws + 196608);
    float2* cniv1 = (float2*)(ws + 200704);

    hipLaunchKernelGGL(prepack, dim3(388), dim3(256), 0, stream,
                       c0, ls0, W0, c1, ls1, W1, wpc0, wpc1, wpw0, wpw1, cniv0, cniv1);
    hipLaunchKernelGGL(rbfnet, dim3(GRID), dim3(BLOCK), 0, stream,
                       xin, b0, b1, wpc0, wpc1, wpw0, wpw1, cniv0, cniv1, outp);
}

// Round 10
// 77.905 us; speedup vs baseline: 5.9530x; 1.0151x over previous
//
#include <hip/hip_runtime.h>
#include <math.h>

// x[8192,32] -> RBF(512,d32) -> Lin(64) -> RBF(512,d64) -> Lin(32), MFMA everywhere.
// Round-9: identical to round-8 EXCEPT the prepack block partition is fixed.
// Round-8 bug: wpw0/wpw1 branches got 2x the needed threads; surplus threads
// computed ks in 16..31 and wrote up to 128KB past their region, stomping the
// cniv tables -> absmax 0.54. Now each branch gets exactly its thread count.
// Main kernel: 32 rows/block (grid 256), full-K GEMMs, 3 barriers, hn in-register.
// Fragment maps (validated r5/r7): A row=l&15,k=(l>>4)*8+e; B col=l&15,same k;
// D col=l&15,row=(l>>4)*4+g.

#define NROWS 8192
#define ROWS 32
#define BLOCK 512
#define GRID (NROWS / ROWS)   // 256

typedef __attribute__((ext_vector_type(8))) short short8;
typedef __attribute__((ext_vector_type(4))) float f32x4;

__device__ __forceinline__ short bf16t(float f) {
    return (short)(__float_as_uint(f) >> 16);
}
__device__ __forceinline__ float bf16f(short u) {
    return __uint_as_float(((unsigned)(unsigned short)u) << 16);
}

// ---------------- prepack: params -> bf16 B-frags + cn/iv (wave-parallel) ----------------
// ws layout (bytes):
//   wpc0 [nt32][l64][e8] u16           @ 0       (32 KB)
//   wpc1 [nt32][kk2][l64][e8] u16      @ 32768   (64 KB)
//   wpw0 [ks16][nt4][l64][e8] u16      @ 98304   (64 KB)
//   wpw1 [ks16][nt2][l64][e8] u16      @ 163840  (32 KB)
//   cniv0 float2[512]                  @ 196608  (4 KB)
//   cniv1 float2[512]                  @ 200704  (4 KB)
// Thread budget (exact): wpc0 2048 (b 0..7), wpc1 2048 (b 8..15),
//                        wpw0 4096 (b 16..31), wpw1 2048 (b 32..39). Grid=40.
__global__ void prepack(const float* __restrict__ c0, const float* __restrict__ ls0,
                        const float* __restrict__ W0,
                        const float* __restrict__ c1, const float* __restrict__ ls1,
                        const float* __restrict__ W1,
                        unsigned short* __restrict__ wpc0, unsigned short* __restrict__ wpc1,
                        unsigned short* __restrict__ wpw0, unsigned short* __restrict__ wpw1,
                        float2* __restrict__ cniv0, float2* __restrict__ cniv1)
{
    const int b  = blockIdx.x;
    const int gi = b * 256 + threadIdx.x;
    const int l  = gi & 63, mr = l & 15, kg = l >> 4;

    if (b < 8) {                        // wpc0 + cniv0: 2048 threads, wave == one nt
        const int nt = gi >> 6;         // 0..31
        const float4 v0 = *(const float4*)&c0[(nt * 16 + mr) * 32 + kg * 8];
        const float4 v1 = *(const float4*)&c0[(nt * 16 + mr) * 32 + kg * 8 + 4];
        const float o[8] = {v0.x, v0.y, v0.z, v0.w, v1.x, v1.y, v1.z, v1.w};
        short8 p; float rp = 0.f;
        #pragma unroll
        for (int i = 0; i < 8; ++i) { p[i] = bf16t(o[i]); rp += o[i] * o[i]; }
        *(short8*)&wpc0[(nt * 64 + l) * 8] = p;
        rp += __shfl_xor(rp, 16);
        rp += __shfl_xor(rp, 32);
        if (kg == 0)
            cniv0[nt * 16 + mr] = make_float2(rp, __expf(-2.0f * ls0[nt * 16 + mr]));
    } else if (b < 16) {                // wpc1 + cniv1: 2048 threads, both kk halves
        const int i2 = gi - 2048;       // 0..2047
        const int nt = i2 >> 6;         // 0..31
        float rp = 0.f;
        #pragma unroll
        for (int kk = 0; kk < 2; ++kk) {
            const float4 v0 = *(const float4*)&c1[(nt * 16 + mr) * 64 + kk * 32 + kg * 8];
            const float4 v1 = *(const float4*)&c1[(nt * 16 + mr) * 64 + kk * 32 + kg * 8 + 4];
            const float o[8] = {v0.x, v0.y, v0.z, v0.w, v1.x, v1.y, v1.z, v1.w};
            short8 p;
            #pragma unroll
            for (int i = 0; i < 8; ++i) { p[i] = bf16t(o[i]); rp += o[i] * o[i]; }
            *(short8*)&wpc1[((nt * 2 + kk) * 64 + l) * 8] = p;
        }
        rp += __shfl_xor(rp, 16);
        rp += __shfl_xor(rp, 32);
        if (kg == 0)
            cniv1[nt * 16 + mr] = make_float2(rp, __expf(-2.0f * ls1[nt * 16 + mr]));
    } else if (b < 32) {                // wpw0: 4096 threads exactly
        const int i2 = gi - 4096;       // 0..4095
        const int nt = (i2 >> 6) & 3, ks = i2 >> 8;   // ks 0..15
        const float4 v0 = *(const float4*)&W0[(nt * 16 + mr) * 512 + ks * 32 + kg * 8];
        const float4 v1 = *(const float4*)&W0[(nt * 16 + mr) * 512 + ks * 32 + kg * 8 + 4];
        const float o[8] = {v0.x, v0.y, v0.z, v0.w, v1.x, v1.y, v1.z, v1.w};
        short8 p;
        #pragma unroll
        for (int i = 0; i < 8; ++i) p[i] = bf16t(o[i]);
        *(short8*)&wpw0[((ks * 4 + nt) * 64 + l) * 8] = p;
    } else {                            // wpw1: blocks 32..39, 2048 threads exactly
        const int i2 = gi - 8192;       // 0..2047
        const int nt = (i2 >> 6) & 1, ks = i2 >> 7;   // ks 0..15
        const float4 v0 = *(const float4*)&W1[(nt * 16 + mr) * 512 + ks * 32 + kg * 8];
        const float4 v1 = *(const float4*)&W1[(nt * 16 + mr) * 512 + ks * 32 + kg * 8 + 4];
        const float o[8] = {v0.x, v0.y, v0.z, v0.w, v1.x, v1.y, v1.z, v1.w};
        short8 p;
        #pragma unroll
        for (int i = 0; i < 8; ++i) p[i] = bf16t(o[i]);
        *(short8*)&wpw1[((ks * 2 + nt) * 64 + l) * 8] = p;
    }
}

// ---------------- main fused kernel: 32 rows/block, 3 barriers ----------------
__global__ __launch_bounds__(BLOCK, 2)
void rbfnet(const float* __restrict__ x,
            const float* __restrict__ b0, const float* __restrict__ b1,
            const unsigned short* __restrict__ wpc0, const unsigned short* __restrict__ wpc1,
            const unsigned short* __restrict__ wpw0, const unsigned short* __restrict__ wpw1,
            const float2* __restrict__ cniv0, const float2* __restrict__ cniv1,
            float* __restrict__ out)
{
    __shared__ unsigned short phi_u[32 * 520];   // 33.3 KB, stride 520 (<=2-way banks)
    __shared__ unsigned short hfrag[32 * 72];    // 4.6 KB, stride 72 (<=2-way banks)

    const int t  = threadIdx.x;
    const int l  = t & 63;
    const int w  = t >> 6;        // wave 0..7
    const int mr = l & 15;
    const int kg = l >> 4;
    const int row0 = blockIdx.x * ROWS;

    // ---- Phase A: x A-frags (2 m-tiles) + row norms, register-only ----
    short8 ax0, ax1;
    float rnv[2][4];
    #pragma unroll
    for (int mt = 0; mt < 2; ++mt) {
        const float4 x0 = *(const float4*)&x[(row0 + mt * 16 + mr) * 32 + kg * 8];
        const float4 x1 = *(const float4*)&x[(row0 + mt * 16 + mr) * 32 + kg * 8 + 4];
        const float xo[8] = {x0.x, x0.y, x0.z, x0.w, x1.x, x1.y, x1.z, x1.w};
        float rp = 0.f;
        short8 a;
        #pragma unroll
        for (int i = 0; i < 8; ++i) { a[i] = bf16t(xo[i]); rp += xo[i] * xo[i]; }
        if (mt == 0) ax0 = a; else ax1 = a;
        rp += __shfl_xor(rp, 16);
        rp += __shfl_xor(rp, 32);
        #pragma unroll
        for (int g = 0; g < 4; ++g) rnv[mt][g] = __shfl(rp, 4 * kg + g);
    }

    // ---- Phase B: RBF0, wave w owns nt = 4w..4w+3, both m-tiles ----
    {
        #pragma unroll 2
        for (int q = 0; q < 4; ++q) {
            const int nt = 4 * w + q;
            const int c  = nt * 16 + mr;
            const short8 bc = *(const short8*)&wpc0[(nt * 64 + l) * 8];
            const float2 cv = cniv0[c];
            f32x4 d0 = {0.f, 0.f, 0.f, 0.f}, d1 = {0.f, 0.f, 0.f, 0.f};
            d0 = __builtin_amdgcn_mfma_f32_16x16x32_bf16(ax0, bc, d0, 0, 0, 0);
            d1 = __builtin_amdgcn_mfma_f32_16x16x32_bf16(ax1, bc, d1, 0, 0, 0);
            #pragma unroll
            for (int g = 0; g < 4; ++g) {
                phi_u[(4 * kg + g) * 520 + c] =
                    (unsigned short)bf16t(__expf(-(rnv[0][g] + cv.x - 2.f * d0[g]) * cv.y));
                phi_u[(16 + 4 * kg + g) * 520 + c] =
                    (unsigned short)bf16t(__expf(-(rnv[1][g] + cv.x - 2.f * d1[g]) * cv.y));
            }
        }
    }
    __syncthreads();                                   // B1: phi0 complete

    // ---- Phase C: GEMM0 full-K (K=512, 16 MFMA); wave -> (nt=w&3, mt=w>>2) ----
    {
        const int nt = w & 3, mt = w >> 2;
        f32x4 hD = {0.f, 0.f, 0.f, 0.f};
        #pragma unroll 4
        for (int ks = 0; ks < 16; ++ks) {
            const short8 ap = *(const short8*)&phi_u[(mt * 16 + mr) * 520 + ks * 32 + kg * 8];
            const short8 bw = *(const short8*)&wpw0[((ks * 4 + nt) * 64 + l) * 8];
            hD = __builtin_amdgcn_mfma_f32_16x16x32_bf16(ap, bw, hD, 0, 0, 0);
        }
        const float bj = b0[nt * 16 + mr];
        #pragma unroll
        for (int g = 0; g < 4; ++g)
            hfrag[(mt * 16 + 4 * kg + g) * 72 + nt * 16 + mr] =
                (unsigned short)bf16t(hD[g] + bj);
    }
    __syncthreads();                                   // B2: hfrag complete

    // ---- Phase E: RBF1 (K=64); hn in-register from bf16 h-frags ----
    {
        short8 ah00, ah01, ah10, ah11;   // [mt][kk]
        float hnv[2][4];
        #pragma unroll
        for (int mt = 0; mt < 2; ++mt) {
            const short8 a0 = *(const short8*)&hfrag[(mt * 16 + mr) * 72 + kg * 8];
            const short8 a1 = *(const short8*)&hfrag[(mt * 16 + mr) * 72 + 32 + kg * 8];
            if (mt == 0) { ah00 = a0; ah01 = a1; } else { ah10 = a0; ah11 = a1; }
            float rp = 0.f;
            #pragma unroll
            for (int i = 0; i < 8; ++i) {
                const float v0 = bf16f(a0[i]), v1 = bf16f(a1[i]);
                rp += v0 * v0 + v1 * v1;
            }
            rp += __shfl_xor(rp, 16);
            rp += __shfl_xor(rp, 32);
            #pragma unroll
            for (int g = 0; g < 4; ++g) hnv[mt][g] = __shfl(rp, 4 * kg + g);
        }
        #pragma unroll 2
        for (int q = 0; q < 4; ++q) {
            const int nt = 4 * w + q;
            const int c  = nt * 16 + mr;
            const short8 bc0 = *(const short8*)&wpc1[((nt * 2 + 0) * 64 + l) * 8];
            const short8 bc1 = *(const short8*)&wpc1[((nt * 2 + 1) * 64 + l) * 8];
            const float2 cv = cniv1[c];
            f32x4 d0 = {0.f, 0.f, 0.f, 0.f}, d1 = {0.f, 0.f, 0.f, 0.f};
            d0 = __builtin_amdgcn_mfma_f32_16x16x32_bf16(ah00, bc0, d0, 0, 0, 0);
            d0 = __builtin_amdgcn_mfma_f32_16x16x32_bf16(ah01, bc1, d0, 0, 0, 0);
            d1 = __builtin_amdgcn_mfma_f32_16x16x32_bf16(ah10, bc0, d1, 0, 0, 0);
            d1 = __builtin_amdgcn_mfma_f32_16x16x32_bf16(ah11, bc1, d1, 0, 0, 0);
            #pragma unroll
            for (int g = 0; g < 4; ++g) {
                phi_u[(4 * kg + g) * 520 + c] =
                    (unsigned short)bf16t(__expf(-(hnv[0][g] + cv.x - 2.f * d0[g]) * cv.y));
                phi_u[(16 + 4 * kg + g) * 520 + c] =
                    (unsigned short)bf16t(__expf(-(hnv[1][g] + cv.x - 2.f * d1[g]) * cv.y));
            }
        }
    }
    __syncthreads();                                   // B3: phi1 complete

    // ---- Phase F: GEMM1 full-K (16 MFMA); waves 0-3 -> (nt=w&1, mt=w>>1); direct store ----
    if (w < 4) {
        const int nt = w & 1, mt = w >> 1;
        f32x4 oD = {0.f, 0.f, 0.f, 0.f};
        #pragma unroll 4
        for (int ks = 0; ks < 16; ++ks) {
            const short8 ap = *(const short8*)&phi_u[(mt * 16 + mr) * 520 + ks * 32 + kg * 8];
            const short8 bw = *(const short8*)&wpw1[((ks * 2 + nt) * 64 + l) * 8];
            oD = __builtin_amdgcn_mfma_f32_16x16x32_bf16(ap, bw, oD, 0, 0, 0);
        }
        const float bj = b1[nt * 16 + mr];
        #pragma unroll
        for (int g = 0; g < 4; ++g)
            out[(row0 + mt * 16 + 4 * kg + g) * 32 + nt * 16 + mr] = oD[g] + bj;
    }
}

extern "C" void kernel_launch(void* const* d_in, const int* in_sizes, int n_in,
                              void* d_out, int out_size, void* d_ws, size_t ws_size,
                              hipStream_t stream) {
    const float* xin = (const float*)d_in[0];
    const float* c0  = (const float*)d_in[1];
    const float* ls0 = (const float*)d_in[2];
    const float* W0  = (const float*)d_in[3];
    const float* b0  = (const float*)d_in[4];
    const float* c1  = (const float*)d_in[5];
    const float* ls1 = (const float*)d_in[6];
    const float* W1  = (const float*)d_in[7];
    const float* b1  = (const float*)d_in[8];
    float* outp = (float*)d_out;

    char* ws = (char*)d_ws;
    unsigned short* wpc0 = (unsigned short*)(ws);
    unsigned short* wpc1 = (unsigned short*)(ws + 32768);
    unsigned short* wpw0 = (unsigned short*)(ws + 98304);
    unsigned short* wpw1 = (unsigned short*)(ws + 163840);
    float2* cniv0 = (float2*)(ws + 196608);
    float2* cniv1 = (float2*)(ws + 200704);

    hipLaunchKernelGGL(prepack, dim3(40), dim3(256), 0, stream,
                       c0, ls0, W0, c1, ls1, W1, wpc0, wpc1, wpw0, wpw1, cniv0, cniv1);
    hipLaunchKernelGGL(rbfnet, dim3(GRID), dim3(BLOCK), 0, stream,
                       xin, b0, b1, wpc0, wpc1, wpw0, wpw1, cniv0, cniv1, outp);
}